// Round 9
// baseline (134.453 us; speedup 1.0000x reference)
//
#include <hip/hip_runtime.h>

// Net_3152505995417: tiny GNN forward (N=116, E=6670, HID=64, EDIM=5).
// R10: keep R8's 4-dispatch structure (boundaries are ~1-2us: R0/R8/R9 fit
// dur = 79us fixed [40 fill + 39 graph head/tail] + sum(kernels) + gaps).
// Cut KERNEL time: remove LDS staging of L2-resident single-use data
// (guide Common-mistake #7):
//  kA: weights read direct from L2 (coalesced per-k); edge part 1 thread/EDGE
//      (d1 + whole G row; was 1 thread/element re-reading ea 6x).
//  kB: d1 via wave-uniform loads (460/block used, was staging all 6670);
//      Y1 rows streamed coalesced per-j. Only 1KB sX2 LDS.
//  kC: verbatim R0 (already direct).
//  kDEF: drop 29.7KB Y2 stage (stream in E); tiny sS/sDv kept; atomic P +
//      last-block F verbatim R8.
// All fma chains / loop orders identical to R0-verified code => bit-identical.

#define NN   116
#define EE   6670
#define HID  64
#define EDIM 5
#define OUTD 4
#define ENC  122
#define EPSF 1e-10f
#define NH   (NN*HID)   // 7424

__device__ __forceinline__ int eid_ij(int i, int j) {
    int a = i < j ? i : j;
    int b = i < j ? j : i;
    return a*NN - ((a*(a+1)) >> 1) + (b - a - 1);   // triu k=1 row-major
}

// kA: node blocks (0..28): X row = enc@W_enc+b_enc (direct), Y1 = Xrow@W1 (direct).
//     edge blocks (29..55): one thread per edge: d1[e] and G row.
__global__ __launch_bounds__(256) void kA(
    const float* __restrict__ enc, const float* __restrict__ ea,
    const float* __restrict__ W_enc, const float* __restrict__ b_enc,
    const float* __restrict__ p1, const float* __restrict__ We,
    const float* __restrict__ W1,
    float* __restrict__ Y1, float* __restrict__ d1, float* __restrict__ G)
{
    const int tid = threadIdx.x;
    if (blockIdx.x < 29) {
        __shared__ float sX[4*HID];
        const int w = tid >> 6, h = tid & 63;
        const int i = blockIdx.x*4 + w;
        const float* er = enc + i*ENC;          // wave-uniform row (bcast loads)
        float acc = b_enc[h];
        #pragma unroll 4
        for (int k = 0; k < ENC; ++k) acc = fmaf(er[k], W_enc[k*HID + h], acc);
        sX[w*HID + h] = acc;
        __syncthreads();
        float a2 = 0.f;
        const float* xr = sX + w*HID;
        #pragma unroll 8
        for (int k = 0; k < HID; ++k) a2 = fmaf(xr[k], W1[k*HID + h], a2);
        Y1[i*HID + h] = a2;
    } else {
        const int e = (blockIdx.x - 29)*256 + tid;
        if (e < EE) {
            const float* r = ea + e*EDIM;
            float rv[EDIM];
            #pragma unroll
            for (int m = 0; m < EDIM; ++m) rv[m] = r[m];
            float a0 = 0.f;
            #pragma unroll
            for (int k = 0; k < EDIM; ++k) a0 = fmaf(rv[k], p1[k], a0);
            d1[e] = a0;
            #pragma unroll
            for (int k = 0; k < EDIM; ++k) {
                float g = 0.f;
                #pragma unroll
                for (int m = 0; m < EDIM; ++m) g = fmaf(fmaxf(rv[m], 0.f), We[m*EDIM + k], g);
                G[e*EDIM + k] = g;
            }
        }
    }
}

// kB: x2 row = relu(D1@Y1 + b1) (direct d1/Y1 reads); dv[i] = x2row.pe;
//     Y2 row = x2row @ W2 (direct). Block 0 zeroes P and cnt.
__global__ __launch_bounds__(256) void kB(
    const float* __restrict__ d1, const float* __restrict__ Y1,
    const float* __restrict__ b1, const float* __restrict__ pe,
    const float* __restrict__ W2,
    float* __restrict__ dv, float* __restrict__ Y2,
    float* __restrict__ P, int* __restrict__ cnt)
{
    __shared__ float sX2[4*HID];
    const int tid = threadIdx.x;
    if (blockIdx.x == 0) {
        if (tid < HID) P[tid] = 0.f;
        if (tid == 0) *cnt = 0;
    }
    const int w = tid >> 6, h = tid & 63;
    const int i = blockIdx.x*4 + w;
    float acc = b1[h];
    #pragma unroll 4
    for (int j = 0; j < NN; ++j) {
        int jj = (j == i) ? (j ^ 1) : j;
        float wgt = (j == i) ? 0.f : d1[eid_ij(i, jj)];   // wave-uniform (1 line)
        acc = fmaf(wgt, Y1[jj*HID + h], acc);             // coalesced row
    }
    float v = fmaxf(acc, 0.f);
    float r = v * pe[h];
    #pragma unroll
    for (int off = 32; off > 0; off >>= 1) r += __shfl_down(r, off, 64);
    if (h == 0) dv[i] = r;
    sX2[w*HID + h] = v;
    __syncthreads();
    float a2 = 0.f;
    const float* xr = sX2 + w*HID;
    #pragma unroll 8
    for (int k = 0; k < HID; ++k) a2 = fmaf(xr[k], W2[k*HID + h], a2);
    Y2[i*HID + h] = a2;
}

// kC: S[i,k] = sum_{j!=i} G[eid(i,j),k] / (max(dv[i],dv[j],0)+eps)
//     one wave per (i,k): 580 waves = 145 blocks x 256. Lanes split j.
__global__ __launch_bounds__(256) void kC(
    const float* __restrict__ G, const float* __restrict__ dv,
    float* __restrict__ S)
{
    const int wg = blockIdx.x*4 + (threadIdx.x >> 6);   // 0..579
    const int lane = threadIdx.x & 63;
    const int i = wg / EDIM, k = wg - i*EDIM;
    const float di = dv[i];
    float acc = 0.f;
    #pragma unroll
    for (int rep = 0; rep < 2; ++rep) {
        int j = lane + rep*64;
        if (j < NN && j != i) {
            float cm = fmaxf(fmaxf(di, dv[j]), 0.f) + EPSF;
            acc += G[eid_ij(i, j)*EDIM + k] / cm;
        }
    }
    #pragma unroll
    for (int off = 32; off > 0; off >>= 1) acc += __shfl_down(acc, off, 64);
    if (lane == 0) S[wg] = acc;
}

// kDEF: per block (29 blocks, 4 rows): tiny sS/sDv stage; d2 own rows;
//   x3 rows with DIRECT Y2 streaming; pool -> atomicAdd P; last block head.
__global__ __launch_bounds__(256) void kDEF(
    const float* __restrict__ G, const float* __restrict__ dvg,
    const float* __restrict__ Sg, const float* __restrict__ Y2,
    const float* __restrict__ be, const float* __restrict__ p2,
    const float* __restrict__ b2, const float* __restrict__ Wl,
    const float* __restrict__ bl,
    float* __restrict__ P, int* __restrict__ cnt, float* __restrict__ out)
{
    __shared__ float sS[NN*EDIM];              // 2320 B
    __shared__ float sDv[NN];
    __shared__ float sD2[4*NN];
    __shared__ float sR[4*HID];
    __shared__ int sLast;
    const int tid = threadIdx.x;
    const int wid = tid >> 6, lane = tid & 63;

    float ber[EDIM], p2r[EDIM];
    #pragma unroll
    for (int k = 0; k < EDIM; ++k) { ber[k] = be[k]; p2r[k] = p2[k]; }

    for (int u = tid; u < NN*EDIM; u += 256) sS[u] = Sg[u];
    if (tid < NN) sDv[tid] = dvg[tid];
    __syncthreads();

    // ---- D: d2 for the block's own 4 rows (460 edges, G direct) ----
    {
        const int i = blockIdx.x*4 + wid;
        #pragma unroll
        for (int rep = 0; rep < 2; ++rep) {
            const int j = lane + rep*64;
            if (j < NN) {
                float val = 0.f;
                if (j != i) {
                    const int a = i < j ? i : j, b = i < j ? j : i;
                    const int e = a*NN - ((a*(a+1)) >> 1) + (b - a - 1);
                    const float da = sDv[a], db = sDv[b];
                    const float rc = 1.f / (fmaxf(fmaxf(da, db), 0.f) + EPSF);
                    #pragma unroll
                    for (int k = 0; k < EDIM; ++k) {
                        const float gp = G[e*EDIM + k] * rc;
                        const float v = fmaf(da, sS[a*EDIM + k] - gp,
                                       fmaf(db, sS[b*EDIM + k] - gp, ber[k]));
                        val = fmaf(fmaxf(v, 0.f), p2r[k], val);
                    }
                }
                sD2[wid*NN + j] = val;
            }
        }
    }
    __syncthreads();

    // ---- E: x3 row = D2@Y2 + b2 (Y2 streamed coalesced), partial pool ----
    {
        float acc = b2[lane];
        const float* d2r = sD2 + wid*NN;
        #pragma unroll 4
        for (int j = 0; j < NN; ++j)
            acc = fmaf(d2r[j], Y2[j*HID + lane], acc);
        sR[wid*HID + lane] = acc;
    }
    __syncthreads();
    if (wid == 0) {
        float s4 = sR[lane] + sR[HID + lane] + sR[2*HID + lane] + sR[3*HID + lane];
        atomicAdd(&P[lane], s4);
    }
    __syncthreads();

    // ---- F: last block computes out = (P/N)@Wl + bl ----
    if (tid == 0) {
        __threadfence();
        int old = __hip_atomic_fetch_add(cnt, 1, __ATOMIC_ACQ_REL, __HIP_MEMORY_SCOPE_AGENT);
        sLast = (old == 28) ? 1 : 0;
    }
    __syncthreads();
    if (sLast && wid == 0) {
        const float pv = __hip_atomic_load(&P[lane], __ATOMIC_ACQUIRE, __HIP_MEMORY_SCOPE_AGENT);
        const float val = pv * (1.0f / NN);
        float res[OUTD];
        #pragma unroll
        for (int o = 0; o < OUTD; ++o) {
            float r = val * Wl[lane*OUTD + o];
            #pragma unroll
            for (int off = 32; off > 0; off >>= 1) r += __shfl_xor(r, off, 64);
            res[o] = r;
        }
        if (lane < OUTD) out[lane] = res[lane] + bl[lane];
    }
}

extern "C" void kernel_launch(void* const* d_in, const int* in_sizes, int n_in,
                              void* d_out, int out_size, void* d_ws, size_t ws_size,
                              hipStream_t stream)
{
    const float* enc   = (const float*)d_in[0];
    const float* ea    = (const float*)d_in[1];
    const float* W_enc = (const float*)d_in[3];
    const float* b_enc = (const float*)d_in[4];
    const float* W1    = (const float*)d_in[5];
    const float* b1    = (const float*)d_in[6];
    const float* p1    = (const float*)d_in[7];
    const float* We    = (const float*)d_in[8];
    const float* be    = (const float*)d_in[9];
    const float* pe    = (const float*)d_in[10];
    const float* W2    = (const float*)d_in[11];
    const float* b2    = (const float*)d_in[12];
    const float* p2    = (const float*)d_in[13];
    const float* Wl    = (const float*)d_in[14];
    const float* bl    = (const float*)d_in[15];
    float* ws = (float*)d_ws;

    // Workspace (floats):
    float* Y1 = ws;                 // [NH]
    float* Y2 = ws + NH;            // [NH]
    float* d1 = ws + 2*NH;          // [EE]
    float* G  = d1 + EE;            // [EE*EDIM]
    float* dv = G + EE*EDIM;        // [NN]
    float* S  = dv + NN;            // [NN*EDIM]
    float* P  = S + NN*EDIM;        // [HID]
    int*  cnt = (int*)(P + HID);    // [1]
    float* out = (float*)d_out;

    kA<<<29 + (EE + 255)/256, 256, 0, stream>>>(enc, ea, W_enc, b_enc, p1, We, W1, Y1, d1, G);
    kB<<<29, 256, 0, stream>>>(d1, Y1, b1, pe, W2, dv, Y2, P, cnt);
    kC<<<(NN*EDIM)/4, 256, 0, stream>>>(G, dv, S);
    kDEF<<<29, 256, 0, stream>>>(G, dv, S, Y2, be, p2, b2, Wl, bl, P, cnt, out);
}

// Round 10
// 115.031 us; speedup vs baseline: 1.1688x; 1.1688x over previous
//
#include <hip/hip_runtime.h>

// Net_3152505995417: tiny GNN forward (N=116, E=6670, HID=64, EDIM=5).
// R11 = R8 base (verified 116.7us; 4 dispatches = dependency-depth floor;
// calibrated model: dur = 79us fixed + phases + ~4.5us/dispatch) with four
// tail trims:
//  kA edge: 1 thread/EDGE (d1 + whole G row from one ea read; was 1/element).
//  kB: writes x2 (relu) directly; W2 matmul REMOVED (moved to F via
//      mean-linear commute); second syncthreads gone.
//  kC: one wave per row i (29 blocks; G row loaded once, cm once, 5 acc);
//      bit-identical j-order + shfl tree per (i,k).
//  kDEF: E computes Z = D2@x2, pools Z; F: pooled=(P/N)@W2+b2, out=pooled@Wl+bl
//      (exact linear commute, reassociation class passed 4x). Y2 eliminated.
// LDS staging KEPT everywhere hot (R10 lesson: destaging turns high-MLP burst
// stages into dependent L2-latency chains; +18us).

#define NN   116
#define EE   6670
#define HID  64
#define EDIM 5
#define OUTD 4
#define ENC  122
#define EPSF 1e-10f
#define NH   (NN*HID)   // 7424

__device__ __forceinline__ int eid_ij(int i, int j) {
    int a = i < j ? i : j;
    int b = i < j ? j : i;
    return a*NN - ((a*(a+1)) >> 1) + (b - a - 1);   // triu k=1 row-major
}

// kA: node blocks (0..28): X row = enc@W_enc+b_enc (LDS-staged weights),
//     Y1 row = Xrow@W1. Edge blocks (29..55): one thread per edge: d1 + G row.
__global__ __launch_bounds__(256) void kA(
    const float* __restrict__ enc, const float* __restrict__ ea,
    const float* __restrict__ W_enc, const float* __restrict__ b_enc,
    const float* __restrict__ p1, const float* __restrict__ We,
    const float* __restrict__ W1,
    float* __restrict__ Y1, float* __restrict__ d1, float* __restrict__ G)
{
    const int tid = threadIdx.x;
    if (blockIdx.x < 29) {
        __shared__ __align__(16) float sWe[ENC*HID];   // 31232 B
        __shared__ __align__(16) float sW1[HID*HID];   // 16384 B
        __shared__ __align__(16) float sEnc[4*ENC];    //  1952 B
        __shared__ float sX[4*HID];
        {
            const float4* g4 = (const float4*)W_enc; float4* s4 = (float4*)sWe;
            for (int u = tid; u < ENC*HID/4; u += 256) s4[u] = g4[u];
        }
        {
            const float4* g4 = (const float4*)W1; float4* s4 = (float4*)sW1;
            for (int u = tid; u < HID*HID/4; u += 256) s4[u] = g4[u];
        }
        {
            const float4* g4 = (const float4*)(enc + blockIdx.x*4*ENC); // 1952B-aligned
            float4* s4 = (float4*)sEnc;
            for (int u = tid; u < 4*ENC/4; u += 256) s4[u] = g4[u];
        }
        __syncthreads();
        const int w = tid >> 6, h = tid & 63;
        const int i = blockIdx.x*4 + w;
        float acc = b_enc[h];
        const float* er = sEnc + w*ENC;
        #pragma unroll 4
        for (int k = 0; k < ENC; ++k) acc = fmaf(er[k], sWe[k*HID + h], acc);
        sX[w*HID + h] = acc;
        __syncthreads();
        float a2 = 0.f;
        const float* xr = sX + w*HID;
        #pragma unroll 8
        for (int k = 0; k < HID; ++k) a2 = fmaf(xr[k], sW1[k*HID + h], a2);
        Y1[i*HID + h] = a2;
    } else {
        const int e = (blockIdx.x - 29)*256 + tid;
        if (e < EE) {
            const float* r = ea + e*EDIM;
            float rv[EDIM];
            #pragma unroll
            for (int m = 0; m < EDIM; ++m) rv[m] = r[m];
            float a0 = 0.f;
            #pragma unroll
            for (int k = 0; k < EDIM; ++k) a0 = fmaf(rv[k], p1[k], a0);
            d1[e] = a0;
            #pragma unroll
            for (int k = 0; k < EDIM; ++k) {
                float g = 0.f;
                #pragma unroll
                for (int m = 0; m < EDIM; ++m) g = fmaf(fmaxf(rv[m], 0.f), We[m*EDIM + k], g);
                G[e*EDIM + k] = g;
            }
        }
    }
}

// kB: x2 row = relu(D1@Y1 + b1) (LDS-staged); dv[i] = x2row.pe; write x2.
//     (W2 matmul removed -- applied in kDEF's F via mean-linear commute.)
//     Block 0 zeroes P and cnt.
__global__ __launch_bounds__(256) void kB(
    const float* __restrict__ d1, const float* __restrict__ Y1,
    const float* __restrict__ b1, const float* __restrict__ pe,
    float* __restrict__ dv, float* __restrict__ x2,
    float* __restrict__ P, int* __restrict__ cnt)
{
    __shared__ __align__(16) float sY[NH];   // 29696 B
    __shared__ __align__(16) float sD[EE];   // 26680 B
    const int tid = threadIdx.x;
    if (blockIdx.x == 0) {
        if (tid < HID) P[tid] = 0.f;
        if (tid == 0) *cnt = 0;
    }
    {
        const float4* g4 = (const float4*)Y1; float4* s4 = (float4*)sY;
        for (int u = tid; u < NH/4; u += 256) s4[u] = g4[u];
        const float2* g2 = (const float2*)d1; float2* s2 = (float2*)sD;
        for (int u = tid; u < EE/2; u += 256) s2[u] = g2[u];
    }
    __syncthreads();
    const int w = tid >> 6, h = tid & 63;
    const int i = blockIdx.x*4 + w;
    float acc = b1[h];
    #pragma unroll 4
    for (int j = 0; j < NN; ++j) {
        int jj = (j == i) ? (j ^ 1) : j;
        float wgt = (j == i) ? 0.f : sD[eid_ij(i, jj)];
        acc = fmaf(wgt, sY[jj*HID + h], acc);
    }
    float v = fmaxf(acc, 0.f);
    float r = v * pe[h];
    #pragma unroll
    for (int off = 32; off > 0; off >>= 1) r += __shfl_down(r, off, 64);
    if (h == 0) dv[i] = r;
    x2[i*HID + h] = v;
}

// kC: one wave per row i (29 blocks x 4 waves = 116). Lane j loads the whole
//     G row (5 floats) once, cm once; 5 accumulators; same shfl tree per k.
//     Bit-identical per (i,k) to the R0/R8 kC.
__global__ __launch_bounds__(256) void kC(
    const float* __restrict__ G, const float* __restrict__ dv,
    float* __restrict__ S)
{
    const int i = blockIdx.x*4 + (threadIdx.x >> 6);    // 0..115
    const int lane = threadIdx.x & 63;
    const float di = dv[i];
    float acc[EDIM] = {0.f, 0.f, 0.f, 0.f, 0.f};
    #pragma unroll
    for (int rep = 0; rep < 2; ++rep) {
        const int j = lane + rep*64;
        if (j < NN && j != i) {
            const float cm = fmaxf(fmaxf(di, dv[j]), 0.f) + EPSF;
            const float* gr = G + eid_ij(i, j)*EDIM;
            #pragma unroll
            for (int k = 0; k < EDIM; ++k) acc[k] += gr[k] / cm;
        }
    }
    #pragma unroll
    for (int k = 0; k < EDIM; ++k) {
        #pragma unroll
        for (int off = 32; off > 0; off >>= 1) acc[k] += __shfl_down(acc[k], off, 64);
    }
    if (lane == 0) {
        #pragma unroll
        for (int k = 0; k < EDIM; ++k) S[i*EDIM + k] = acc[k];
    }
}

// kDEF: per block (29 blocks, 4 rows): stage x2 + S + dv; d2 own rows;
//   Z row = D2@x2; pool Z -> atomicAdd P; last block: pooled=(P/N)@W2+b2,
//   out = pooled@Wl + bl.
__global__ __launch_bounds__(256) void kDEF(
    const float* __restrict__ G, const float* __restrict__ dvg,
    const float* __restrict__ Sg, const float* __restrict__ x2,
    const float* __restrict__ be, const float* __restrict__ p2,
    const float* __restrict__ W2, const float* __restrict__ b2,
    const float* __restrict__ Wl, const float* __restrict__ bl,
    float* __restrict__ P, int* __restrict__ cnt, float* __restrict__ out)
{
    __shared__ __align__(16) float sY[NH];     // x2 tile, 29696 B
    __shared__ float sS[NN*EDIM];
    __shared__ float sDv[NN];
    __shared__ float sD2[4*NN];
    __shared__ float sR[4*HID];
    __shared__ int sLast;
    const int tid = threadIdx.x;
    const int wid = tid >> 6, lane = tid & 63;

    float ber[EDIM], p2r[EDIM];
    #pragma unroll
    for (int k = 0; k < EDIM; ++k) { ber[k] = be[k]; p2r[k] = p2[k]; }

    {
        const float4* g4 = (const float4*)x2; float4* s4 = (float4*)sY;
        for (int u = tid; u < NH/4; u += 256) s4[u] = g4[u];
    }
    for (int u = tid; u < NN*EDIM; u += 256) sS[u] = Sg[u];
    if (tid < NN) sDv[tid] = dvg[tid];
    __syncthreads();

    // ---- D: d2 for the block's own 4 rows (460 edges, G direct) ----
    {
        const int i = blockIdx.x*4 + wid;
        #pragma unroll
        for (int rep = 0; rep < 2; ++rep) {
            const int j = lane + rep*64;
            if (j < NN) {
                float val = 0.f;
                if (j != i) {
                    const int a = i < j ? i : j, b = i < j ? j : i;
                    const int e = a*NN - ((a*(a+1)) >> 1) + (b - a - 1);
                    const float da = sDv[a], db = sDv[b];
                    const float rc = 1.f / (fmaxf(fmaxf(da, db), 0.f) + EPSF);
                    #pragma unroll
                    for (int k = 0; k < EDIM; ++k) {
                        const float gp = G[e*EDIM + k] * rc;
                        const float v = fmaf(da, sS[a*EDIM + k] - gp,
                                       fmaf(db, sS[b*EDIM + k] - gp, ber[k]));
                        val = fmaf(fmaxf(v, 0.f), p2r[k], val);
                    }
                }
                sD2[wid*NN + j] = val;
            }
        }
    }
    __syncthreads();

    // ---- E: Z row = D2@x2 (b2 deferred to F), partial pool ----
    {
        float acc = 0.f;
        const float* d2r = sD2 + wid*NN;
        #pragma unroll 4
        for (int j = 0; j < NN; ++j)
            acc = fmaf(d2r[j], sY[j*HID + lane], acc);
        sR[wid*HID + lane] = acc;
    }
    __syncthreads();
    if (wid == 0) {
        float s4 = sR[lane] + sR[HID + lane] + sR[2*HID + lane] + sR[3*HID + lane];
        atomicAdd(&P[lane], s4);
    }
    __syncthreads();

    // ---- F: last block: pooled = (P/N)@W2 + b2 ; out = pooled@Wl + bl ----
    if (tid == 0) {
        __threadfence();
        int old = __hip_atomic_fetch_add(cnt, 1, __ATOMIC_ACQ_REL, __HIP_MEMORY_SCOPE_AGENT);
        sLast = (old == 28) ? 1 : 0;
    }
    __syncthreads();
    if (sLast && wid == 0) {
        const float pv = __hip_atomic_load(&P[lane], __ATOMIC_ACQUIRE, __HIP_MEMORY_SCOPE_AGENT);
        const float zbar = pv * (1.0f / NN);
        float q = b2[lane];
        #pragma unroll 8
        for (int j = 0; j < HID; ++j)
            q = fmaf(__shfl(zbar, j, 64), W2[j*HID + lane], q);
        float res[OUTD];
        #pragma unroll
        for (int o = 0; o < OUTD; ++o) {
            float r = q * Wl[lane*OUTD + o];
            #pragma unroll
            for (int off = 32; off > 0; off >>= 1) r += __shfl_xor(r, off, 64);
            res[o] = r;
        }
        if (lane < OUTD) out[lane] = res[lane] + bl[lane];
    }
}

extern "C" void kernel_launch(void* const* d_in, const int* in_sizes, int n_in,
                              void* d_out, int out_size, void* d_ws, size_t ws_size,
                              hipStream_t stream)
{
    const float* enc   = (const float*)d_in[0];
    const float* ea    = (const float*)d_in[1];
    const float* W_enc = (const float*)d_in[3];
    const float* b_enc = (const float*)d_in[4];
    const float* W1    = (const float*)d_in[5];
    const float* b1    = (const float*)d_in[6];
    const float* p1    = (const float*)d_in[7];
    const float* We    = (const float*)d_in[8];
    const float* be    = (const float*)d_in[9];
    const float* pe    = (const float*)d_in[10];
    const float* W2    = (const float*)d_in[11];
    const float* b2    = (const float*)d_in[12];
    const float* p2    = (const float*)d_in[13];
    const float* Wl    = (const float*)d_in[14];
    const float* bl    = (const float*)d_in[15];
    float* ws = (float*)d_ws;

    // Workspace (floats):
    float* Y1 = ws;                 // [NH]
    float* x2 = ws + NH;            // [NH]  (replaces Y2)
    float* d1 = ws + 2*NH;          // [EE]
    float* G  = d1 + EE;            // [EE*EDIM]
    float* dv = G + EE*EDIM;        // [NN]
    float* S  = dv + NN;            // [NN*EDIM]
    float* P  = S + NN*EDIM;        // [HID]
    int*  cnt = (int*)(P + HID);    // [1]
    float* out = (float*)d_out;

    kA<<<29 + (EE + 255)/256, 256, 0, stream>>>(enc, ea, W_enc, b_enc, p1, We, W1, Y1, d1, G);
    kB<<<29, 256, 0, stream>>>(d1, Y1, b1, pe, dv, x2, P, cnt);
    kC<<<29, 256, 0, stream>>>(G, dv, S);
    kDEF<<<29, 256, 0, stream>>>(G, dv, S, x2, be, p2, W2, b2, Wl, bl, P, cnt, out);
}